// Round 1
// baseline (221.495 us; speedup 1.0000x reference)
//
#include <hip/hip_runtime.h>
#include <hip/hip_bf16.h>

using u16 = unsigned short;
typedef __attribute__((ext_vector_type(4))) float f32x4;
typedef __attribute__((ext_vector_type(8))) __bf16 bf16x8;
typedef __attribute__((ext_vector_type(8))) short s16x8;
typedef __attribute__((ext_vector_type(4))) short s16x4;

#define DEVI __device__ __forceinline__

constexpr int BATCH = 2, C = 512, HW = 4096, NG = 32, CPG = 16;

DEVI float b2f(u16 u) { union { unsigned u; float f; } a; a.u = ((unsigned)u) << 16; return a.f; }
DEVI u16 f2b(float f) {
  union { float f; unsigned u; } a; a.f = f;
  unsigned r = a.u + 0x7fffu + ((a.u >> 16) & 1u);
  return (u16)(r >> 16);
}

// ---------------- fp32 weights -> bf16 ----------------
__global__ __launch_bounds__(256) void cvt_w(const float* __restrict__ a, const float* __restrict__ b,
                                             const float* __restrict__ c, const float* __restrict__ d,
                                             u16* __restrict__ out) {
  int i = blockIdx.x * 256 + threadIdx.x;  // 0..262143, 4 floats each
  int w = i >> 16;
  int off = (i & 65535) * 4;
  const float* s = (w == 0) ? a : (w == 1) ? b : (w == 2) ? c : d;
  f32x4 v = *(const f32x4*)(s + off);
  s16x4 o;
  o[0] = (short)f2b(v[0]); o[1] = (short)f2b(v[1]); o[2] = (short)f2b(v[2]); o[3] = (short)f2b(v[3]);
  *(s16x4*)(out + (size_t)w * 262144 + off) = o;
}

// ---------------- GroupNorm stats: one block per (b,g) ----------------
__global__ __launch_bounds__(1024) void gn_stats(const float* __restrict__ x, float* __restrict__ stats) {
  int bg = blockIdx.x;  // 0..63
  const f32x4* xg = (const f32x4*)(x + (size_t)bg * (CPG * HW));
  float s = 0.f, ss = 0.f;
  for (int i = threadIdx.x; i < CPG * HW / 4; i += 1024) {
    f32x4 v = xg[i];
    s += v[0] + v[1] + v[2] + v[3];
    ss += v[0] * v[0] + v[1] * v[1] + v[2] * v[2] + v[3] * v[3];
  }
  #pragma unroll
  for (int o = 32; o; o >>= 1) { s += __shfl_xor(s, o); ss += __shfl_xor(ss, o); }
  __shared__ float red[32];
  int wv = threadIdx.x >> 6, ln = threadIdx.x & 63;
  if (ln == 0) { red[wv] = s; red[16 + wv] = ss; }
  __syncthreads();
  if (threadIdx.x == 0) {
    float S = 0.f, SS = 0.f;
    for (int i = 0; i < 16; ++i) { S += red[i]; SS += red[16 + i]; }
    float inv = 1.f / (float)(CPG * HW);
    float mean = S * inv;
    float var = SS * inv - mean * mean;
    stats[bg * 2] = mean;
    stats[bg * 2 + 1] = rsqrtf(var + 1e-6f);
  }
}

// ---------------- normalize + transpose: x[b][c][hw] -> hnT[b][hw][c] (bf16) ----------------
__global__ __launch_bounds__(256) void gn_normT(const float* __restrict__ x, const float* __restrict__ stats,
                                                const float* __restrict__ gamma, const float* __restrict__ beta,
                                                u16* __restrict__ hnT) {
  __shared__ u16 tile[64][66];
  int b = blockIdx.z, c0 = blockIdx.y * 64, h0 = blockIdx.x * 64;
  int t = threadIdx.x;
  const float* xb = x + ((size_t)b * C + c0) * HW + h0;
  int r = t / 16, cc = (t % 16) * 4;
  #pragma unroll
  for (int it = 0; it < 4; ++it) {
    int rr = it * 16 + r;
    int ch = c0 + rr;
    int g = b * NG + (ch >> 4);  // CPG = 16
    float mean = stats[g * 2], rstd = stats[g * 2 + 1];
    float ga = gamma[ch] * rstd;
    float be = beta[ch] - mean * ga;
    f32x4 v = *(const f32x4*)(xb + (size_t)rr * HW + cc);
    #pragma unroll
    for (int j = 0; j < 4; ++j) tile[rr][cc + j] = f2b(v[j] * ga + be);
  }
  __syncthreads();
  u16* op = hnT + (size_t)b * HW * C + (size_t)h0 * C + c0;
  int hr2 = t / 8, cg = (t % 8) * 8;
  #pragma unroll
  for (int it = 0; it < 2; ++it) {
    int hr = it * 32 + hr2;
    s16x8 o8;
    #pragma unroll
    for (int j = 0; j < 8; ++j) o8[j] = (short)tile[cg + j][hr];
    *(s16x8*)(op + (size_t)hr * C + cg) = o8;
  }
}

// ---------------- GEMM: D[m][n] = sum_k A[m][k] * Bt[n][k]  (bf16 in, fp32 acc) ----------------
#define EPI_BIAS_M 1
#define EPI_BIAS_N 2
#define EPI_RESID  4
#define EPI_F32OUT 8
#define EPI_SCALE  16

template <int EPI>
__global__ __launch_bounds__(256) void gemm_bt(const u16* __restrict__ A, const u16* __restrict__ Bt,
                                               void* __restrict__ Co, int M, int N, int K,
                                               long long sA, long long sB, long long sC,
                                               const float* __restrict__ bias,
                                               const float* __restrict__ resid, long long sR, float scale) {
  (void)M;
  __shared__ u16 ldsA[128 * 64];
  __shared__ u16 ldsB[128 * 64];
  const int tid = threadIdx.x;
  const int bz = blockIdx.z;
  const int bm = blockIdx.y, bn = blockIdx.x;
  A += (size_t)bz * sA;
  Bt += (size_t)bz * sB;
  const int wave = tid >> 6, lane = tid & 63;
  const int wr = wave >> 1, wc = wave & 1;
  f32x4 acc[4][4] = {};

  // staging constants: thread t stages LDS row (cc*32 + t/8), chunk t%8; the global
  // source chunk is XOR-swizzled so that ds_read applies the same involution.
  const int srow = tid >> 3;                 // 0..31
  const int sch = (tid & 7) ^ (srow & 7);    // pre-swizzled global chunk
  const u16* gA = A + (size_t)(bm * 128 + srow) * K + sch * 8;
  const u16* gB = Bt + (size_t)(bn * 128 + srow) * K + sch * 8;
  u16* lA = ldsA + wave * 512;  // wave-uniform base (bytes: wave*1024)
  u16* lB = ldsB + wave * 512;

  for (int k0 = 0; k0 < K; k0 += 64) {
    #pragma unroll
    for (int cc = 0; cc < 4; ++cc) {
      __builtin_amdgcn_global_load_lds(
          (const __attribute__((address_space(1))) void*)(gA + (size_t)cc * 32 * K + k0),
          (__attribute__((address_space(3))) void*)(lA + cc * 2048), 16, 0, 0);
      __builtin_amdgcn_global_load_lds(
          (const __attribute__((address_space(1))) void*)(gB + (size_t)cc * 32 * K + k0),
          (__attribute__((address_space(3))) void*)(lB + cc * 2048), 16, 0, 0);
    }
    __syncthreads();
    #pragma unroll
    for (int kk = 0; kk < 2; ++kk) {
      bf16x8 af[4], bfv[4];
      #pragma unroll
      for (int m = 0; m < 4; ++m) {
        int r = wr * 64 + m * 16 + (lane & 15);
        int chunk = (kk * 4 + (lane >> 4)) ^ (r & 7);
        af[m] = *(const bf16x8*)(ldsA + r * 64 + chunk * 8);
      }
      #pragma unroll
      for (int n = 0; n < 4; ++n) {
        int r = wc * 64 + n * 16 + (lane & 15);
        int chunk = (kk * 4 + (lane >> 4)) ^ (r & 7);
        bfv[n] = *(const bf16x8*)(ldsB + r * 64 + chunk * 8);
      }
      #pragma unroll
      for (int m = 0; m < 4; ++m)
        #pragma unroll
        for (int n = 0; n < 4; ++n)
          acc[m][n] = __builtin_amdgcn_mfma_f32_16x16x32_bf16(af[m], bfv[n], acc[m][n], 0, 0, 0);
    }
    __syncthreads();
  }

  // epilogue: D mapping col = lane&15, row = (lane>>4)*4 + reg
  const int col0 = bn * 128 + wc * 64;
  const int row0 = bm * 128 + wr * 64 + ((lane >> 4) << 2);
  #pragma unroll
  for (int m = 0; m < 4; ++m) {
    #pragma unroll
    for (int j = 0; j < 4; ++j) {
      int gm = row0 + m * 16 + j;
      float bm_v = (EPI & EPI_BIAS_M) ? bias[gm] : 0.f;
      #pragma unroll
      for (int n = 0; n < 4; ++n) {
        int gn = col0 + n * 16 + (lane & 15);
        float v = acc[m][n][j];
        if (EPI & EPI_SCALE) v *= scale;
        v += bm_v;
        if (EPI & EPI_BIAS_N) v += bias[gn];
        if (EPI & EPI_RESID) v += resid[(size_t)bz * sR + (size_t)gm * N + gn];
        if (EPI & EPI_F32OUT)
          ((float*)Co)[(size_t)bz * sC + (size_t)gm * N + gn] = v;
        else
          ((u16*)Co)[(size_t)bz * sC + (size_t)gm * N + gn] = f2b(v);
      }
    }
  }
}

// ---------------- row softmax in place on S (bf16), one wave per row ----------------
__global__ __launch_bounds__(256) void softmax_rows(u16* __restrict__ S) {
  int row = blockIdx.x * 4 + (threadIdx.x >> 6);
  int lane = threadIdx.x & 63;
  s16x8* p = (s16x8*)(S + (size_t)row * 4096);
  float v[64];
  float m = -1e30f;
  #pragma unroll
  for (int j = 0; j < 8; ++j) {
    s16x8 raw = p[j * 64 + lane];
    #pragma unroll
    for (int e = 0; e < 8; ++e) {
      float f = b2f((u16)raw[e]);
      v[j * 8 + e] = f;
      m = fmaxf(m, f);
    }
  }
  #pragma unroll
  for (int o = 32; o; o >>= 1) m = fmaxf(m, __shfl_xor(m, o));
  float s = 0.f;
  #pragma unroll
  for (int i = 0; i < 64; ++i) { v[i] = __expf(v[i] - m); s += v[i]; }
  #pragma unroll
  for (int o = 32; o; o >>= 1) s += __shfl_xor(s, o);
  float r = 1.f / s;
  #pragma unroll
  for (int j = 0; j < 8; ++j) {
    s16x8 o8;
    #pragma unroll
    for (int e = 0; e < 8; ++e) o8[e] = (short)f2b(v[j * 8 + e] * r);
    p[j * 64 + lane] = o8;
  }
}

extern "C" void kernel_launch(void* const* d_in, const int* in_sizes, int n_in,
                              void* d_out, int out_size, void* d_ws, size_t ws_size,
                              hipStream_t stream) {
  (void)in_sizes; (void)n_in; (void)out_size; (void)ws_size;
  const float* x     = (const float*)d_in[0];
  const float* gamma = (const float*)d_in[1];
  const float* beta  = (const float*)d_in[2];
  const float* wq    = (const float*)d_in[3];
  const float* bq    = (const float*)d_in[4];
  const float* wk    = (const float*)d_in[5];
  const float* bk    = (const float*)d_in[6];
  const float* wv    = (const float*)d_in[7];
  const float* bv    = (const float*)d_in[8];
  const float* wo    = (const float*)d_in[9];
  const float* bo    = (const float*)d_in[10];

  char* ws = (char*)d_ws;
  const size_t NTOK = (size_t)HW * C;  // 2M elems
  float* stats = (float*)ws;                      // 1 KiB
  u16* wbf = (u16*)(ws + 1024);                   // 4 x 512x512 bf16 = 2 MiB
  size_t off = 1024 + (size_t)4 * 262144 * 2;
  u16* hnT = (u16*)(ws + off); off += (size_t)BATCH * NTOK * 2;   // 8 MiB
  u16* qT  = (u16*)(ws + off); off += (size_t)BATCH * NTOK * 2;   // 8 MiB
  u16* kT  = (u16*)(ws + off); off += (size_t)BATCH * NTOK * 2;   // 8 MiB
  u16* vv  = (u16*)(ws + off); off += (size_t)BATCH * NTOK * 2;   // 8 MiB
  u16* aoT = (u16*)(ws + off); off += (size_t)BATCH * NTOK * 2;   // 8 MiB
  u16* Sm  = (u16*)(ws + off);                                    // 64 MiB

  const long long sTok = (long long)HW * C;   // 2097152
  const long long sS   = (long long)HW * HW;  // 16777216
  const float scale = 0.044194173824159216f;  // 512^-0.5

  cvt_w<<<dim3(1024), dim3(256), 0, stream>>>(wq, wk, wv, wo, wbf);
  gn_stats<<<dim3(64), dim3(1024), 0, stream>>>(x, stats);
  gn_normT<<<dim3(HW / 64, C / 64, BATCH), dim3(256), 0, stream>>>(x, stats, gamma, beta, hnT);

  // qT[b][i][o] = sum_c hnT[b][i][c] * wq[o][c] + bq[o]
  gemm_bt<EPI_BIAS_N><<<dim3(4, 32, BATCH), dim3(256), 0, stream>>>(
      hnT, wbf + 0 * 262144, qT, HW, C, C, sTok, 0, sTok, bq, nullptr, 0, 0.f);
  gemm_bt<EPI_BIAS_N><<<dim3(4, 32, BATCH), dim3(256), 0, stream>>>(
      hnT, wbf + 1 * 262144, kT, HW, C, C, sTok, 0, sTok, bk, nullptr, 0, 0.f);
  // v[b][o][j] = sum_c wv[o][c] * hnT[b][j][c] + bv[o]
  gemm_bt<EPI_BIAS_M><<<dim3(32, 4, BATCH), dim3(256), 0, stream>>>(
      wbf + 2 * 262144, hnT, vv, C, HW, C, 0, sTok, sTok, bv, nullptr, 0, 0.f);
  // S[b][i][j] = scale * sum_c qT[b][i][c] * kT[b][j][c]
  gemm_bt<EPI_SCALE><<<dim3(32, 32, BATCH), dim3(256), 0, stream>>>(
      qT, kT, Sm, HW, HW, C, sTok, sTok, sS, nullptr, nullptr, 0, scale);
  // softmax rows (8192 rows, wave per row)
  softmax_rows<<<dim3(2048), dim3(256), 0, stream>>>(Sm);
  // aoT[b][i][c] = sum_j P[b][i][j] * v[b][c][j]
  gemm_bt<0><<<dim3(4, 32, BATCH), dim3(256), 0, stream>>>(
      Sm, vv, aoT, HW, C, HW, sS, sTok, sTok, nullptr, nullptr, 0, 0.f);
  // out[b][o][i] = x[b][o][i] + bo[o] + sum_c wo[o][c] * aoT[b][i][c]
  gemm_bt<EPI_BIAS_M | EPI_RESID | EPI_F32OUT><<<dim3(32, 4, BATCH), dim3(256), 0, stream>>>(
      wbf + 3 * 262144, aoT, d_out, C, HW, C, 0, sTok, (long long)C * HW, bo, x, (long long)C * HW, 0.f);
}

// Round 2
// 190.735 us; speedup vs baseline: 1.1613x; 1.1613x over previous
//
#include <hip/hip_runtime.h>
#include <hip/hip_bf16.h>

using u16 = unsigned short;
typedef __attribute__((ext_vector_type(4))) float f32x4;
typedef __attribute__((ext_vector_type(8))) __bf16 bf16x8;
typedef __attribute__((ext_vector_type(8))) short s16x8;
typedef __attribute__((ext_vector_type(4))) short s16x4;

#define DEVI __device__ __forceinline__

constexpr int BATCH = 2, C = 512, HW = 4096, NG = 32, CPG = 16;

DEVI float b2f(u16 u) { union { unsigned u; float f; } a; a.u = ((unsigned)u) << 16; return a.f; }
DEVI u16 f2b(float f) {
  union { float f; unsigned u; } a; a.f = f;
  unsigned r = a.u + 0x7fffu + ((a.u >> 16) & 1u);
  return (u16)(r >> 16);
}

// ---------------- fp32 weights -> bf16 ----------------
__global__ __launch_bounds__(256) void cvt_w(const float* __restrict__ a, const float* __restrict__ b,
                                             const float* __restrict__ c, const float* __restrict__ d,
                                             u16* __restrict__ out) {
  int i = blockIdx.x * 256 + threadIdx.x;
  int w = i >> 16;
  int off = (i & 65535) * 4;
  const float* s = (w == 0) ? a : (w == 1) ? b : (w == 2) ? c : d;
  f32x4 v = *(const f32x4*)(s + off);
  s16x4 o;
  o[0] = (short)f2b(v[0]); o[1] = (short)f2b(v[1]); o[2] = (short)f2b(v[2]); o[3] = (short)f2b(v[3]);
  *(s16x4*)(out + (size_t)w * 262144 + off) = o;
}

// ---------------- GroupNorm stats ----------------
__global__ __launch_bounds__(1024) void gn_stats(const float* __restrict__ x, float* __restrict__ stats) {
  int bg = blockIdx.x;
  const f32x4* xg = (const f32x4*)(x + (size_t)bg * (CPG * HW));
  float s = 0.f, ss = 0.f;
  for (int i = threadIdx.x; i < CPG * HW / 4; i += 1024) {
    f32x4 v = xg[i];
    s += v[0] + v[1] + v[2] + v[3];
    ss += v[0] * v[0] + v[1] * v[1] + v[2] * v[2] + v[3] * v[3];
  }
  #pragma unroll
  for (int o = 32; o; o >>= 1) { s += __shfl_xor(s, o); ss += __shfl_xor(ss, o); }
  __shared__ float red[32];
  int wv = threadIdx.x >> 6, ln = threadIdx.x & 63;
  if (ln == 0) { red[wv] = s; red[16 + wv] = ss; }
  __syncthreads();
  if (threadIdx.x == 0) {
    float S = 0.f, SS = 0.f;
    for (int i = 0; i < 16; ++i) { S += red[i]; SS += red[16 + i]; }
    float inv = 1.f / (float)(CPG * HW);
    float mean = S * inv;
    float var = SS * inv - mean * mean;
    stats[bg * 2] = mean;
    stats[bg * 2 + 1] = rsqrtf(var + 1e-6f);
  }
}

// ---------------- normalize + transpose ----------------
__global__ __launch_bounds__(256) void gn_normT(const float* __restrict__ x, const float* __restrict__ stats,
                                                const float* __restrict__ gamma, const float* __restrict__ beta,
                                                u16* __restrict__ hnT) {
  __shared__ u16 tile[64][66];
  int b = blockIdx.z, c0 = blockIdx.y * 64, h0 = blockIdx.x * 64;
  int t = threadIdx.x;
  const float* xb = x + ((size_t)b * C + c0) * HW + h0;
  int r = t / 16, cc = (t % 16) * 4;
  #pragma unroll
  for (int it = 0; it < 4; ++it) {
    int rr = it * 16 + r;
    int ch = c0 + rr;
    int g = b * NG + (ch >> 4);
    float mean = stats[g * 2], rstd = stats[g * 2 + 1];
    float ga = gamma[ch] * rstd;
    float be = beta[ch] - mean * ga;
    f32x4 v = *(const f32x4*)(xb + (size_t)rr * HW + cc);
    #pragma unroll
    for (int j = 0; j < 4; ++j) tile[rr][cc + j] = f2b(v[j] * ga + be);
  }
  __syncthreads();
  u16* op = hnT + (size_t)b * HW * C + (size_t)h0 * C + c0;
  int hr2 = t / 8, cg = (t % 8) * 8;
  #pragma unroll
  for (int it = 0; it < 2; ++it) {
    int hr = it * 32 + hr2;
    s16x8 o8;
    #pragma unroll
    for (int j = 0; j < 8; ++j) o8[j] = (short)tile[cg + j][hr];
    *(s16x8*)(op + (size_t)hr * C + cg) = o8;
  }
}

// ---------------- small GEMM (128x128 m97-style), for projections ----------------
#define EPI_BIAS_M 1
#define EPI_BIAS_N 2
#define EPI_RESID  4
#define EPI_F32OUT 8

template <int EPI>
__global__ __launch_bounds__(256) void gemm_bt(const u16* __restrict__ A, const u16* __restrict__ Bt,
                                               void* __restrict__ Co, int M, int N, int K,
                                               long long sA, long long sB, long long sC,
                                               const float* __restrict__ bias,
                                               const float* __restrict__ resid, long long sR) {
  (void)M;
  __shared__ u16 ldsA[128 * 64];
  __shared__ u16 ldsB[128 * 64];
  const int tid = threadIdx.x;
  const int bz = blockIdx.z;
  const int bm = blockIdx.y, bn = blockIdx.x;
  A += (size_t)bz * sA;
  Bt += (size_t)bz * sB;
  const int wave = tid >> 6, lane = tid & 63;
  const int wr = wave >> 1, wc = wave & 1;
  f32x4 acc[4][4] = {};

  const int srow = tid >> 3;
  const int sch = (tid & 7) ^ (srow & 7);
  const u16* gA = A + (size_t)(bm * 128 + srow) * K + sch * 8;
  const u16* gB = Bt + (size_t)(bn * 128 + srow) * K + sch * 8;
  u16* lA = ldsA + wave * 512;
  u16* lB = ldsB + wave * 512;

  for (int k0 = 0; k0 < K; k0 += 64) {
    #pragma unroll
    for (int cc = 0; cc < 4; ++cc) {
      __builtin_amdgcn_global_load_lds(
          (const __attribute__((address_space(1))) void*)(gA + (size_t)cc * 32 * K + k0),
          (__attribute__((address_space(3))) void*)(lA + cc * 2048), 16, 0, 0);
      __builtin_amdgcn_global_load_lds(
          (const __attribute__((address_space(1))) void*)(gB + (size_t)cc * 32 * K + k0),
          (__attribute__((address_space(3))) void*)(lB + cc * 2048), 16, 0, 0);
    }
    __syncthreads();
    #pragma unroll
    for (int kk = 0; kk < 2; ++kk) {
      bf16x8 af[4], bfv[4];
      #pragma unroll
      for (int m = 0; m < 4; ++m) {
        int r = wr * 64 + m * 16 + (lane & 15);
        int chunk = (kk * 4 + (lane >> 4)) ^ (r & 7);
        af[m] = *(const bf16x8*)(ldsA + r * 64 + chunk * 8);
      }
      #pragma unroll
      for (int n = 0; n < 4; ++n) {
        int r = wc * 64 + n * 16 + (lane & 15);
        int chunk = (kk * 4 + (lane >> 4)) ^ (r & 7);
        bfv[n] = *(const bf16x8*)(ldsB + r * 64 + chunk * 8);
      }
      #pragma unroll
      for (int m = 0; m < 4; ++m)
        #pragma unroll
        for (int n = 0; n < 4; ++n)
          acc[m][n] = __builtin_amdgcn_mfma_f32_16x16x32_bf16(af[m], bfv[n], acc[m][n], 0, 0, 0);
    }
    __syncthreads();
  }

  const int col0 = bn * 128 + wc * 64;
  const int row0 = bm * 128 + wr * 64 + ((lane >> 4) << 2);
  #pragma unroll
  for (int m = 0; m < 4; ++m) {
    #pragma unroll
    for (int j = 0; j < 4; ++j) {
      int gm = row0 + m * 16 + j;
      float bm_v = (EPI & EPI_BIAS_M) ? bias[gm] : 0.f;
      #pragma unroll
      for (int n = 0; n < 4; ++n) {
        int gn = col0 + n * 16 + (lane & 15);
        float v = acc[m][n][j] + bm_v;
        if (EPI & EPI_BIAS_N) v += bias[gn];
        if (EPI & EPI_RESID) v += resid[(size_t)bz * sR + (size_t)gm * N + gn];
        if (EPI & EPI_F32OUT)
          ((float*)Co)[(size_t)bz * sC + (size_t)gm * N + gn] = v;
        else
          ((u16*)Co)[(size_t)bz * sC + (size_t)gm * N + gn] = f2b(v);
      }
    }
  }
}

// ---------------- big GEMM: 256x256 tile, 8-phase schedule, counted vmcnt ----------------
// D[m][n] = sum_k A[m][k]*Bt[n][k], both row-major with row stride ldK.
// Optional split-K: blockIdx.z = bz*(2^nsplitLog) + kz, K-range [kz*kLen, +kLen).
template <bool SCALED>
__global__ __launch_bounds__(512, 2) void gemm256(
    const u16* __restrict__ Ag, const u16* __restrict__ Bg,
    u16* __restrict__ Co, u16* __restrict__ Co2, int zSwitch,
    int Nld, int ldK, int nsplitLog, int kLen,
    long long sA, long long sB, long long sC, float scale) {
  __shared__ u16 lds[65536];  // [db][A/B][half] x (128x64), 128 KiB
  const int tid = threadIdx.x;
  const int lane = tid & 63, w = tid >> 6;
  const int wm = w >> 2, wn = w & 3;
  const int l15 = lane & 15, l4 = lane >> 4;
  const int bn = blockIdx.x, bm = blockIdx.y;
  const int z = blockIdx.z;
  const int bz = z >> nsplitLog, kz = z & ((1 << nsplitLog) - 1);
  const int kStart = kz * kLen;
  const int NT = kLen >> 6;

  const int rStage = w * 8 + (lane >> 3);      // 0..63
  const int gch = (lane & 7) ^ (lane >> 3);    // pre-swizzled chunk (both-sides swizzle)
  const u16* gA = Ag + (size_t)bz * sA + (size_t)(bm * 256) * ldK + kStart + gch * 8;
  const u16* gB = Bg + (size_t)bz * sB + (size_t)(bn * 256) * ldK + kStart + gch * 8;

  f32x4 acc[8][4] = {};
  bf16x8 aF[4][2], bF[2][2][2];

  const int hB = wn >> 1, qB = wn & 1;
  const u16* pA0 = lds + (0 * 4 + wm) * 8192;
  const u16* pA1 = lds + (1 * 4 + wm) * 8192;
  const u16* pB0 = lds + (0 * 4 + 2 + hB) * 8192;
  const u16* pB1 = lds + (1 * 4 + 2 + hB) * 8192;

  #define STAGE(TT, DB, AB, HF) { \
    const u16* gbase = (AB) ? gB : gA; \
    u16* l0 = lds + ((DB) * 4 + (AB) * 2 + (HF)) * 8192 + w * 512; \
    _Pragma("unroll") for (int s = 0; s < 2; ++s) { \
      const u16* gp = gbase + (size_t)((HF) * 128 + s * 64 + rStage) * ldK + (TT) * 64; \
      __builtin_amdgcn_global_load_lds((const __attribute__((address_space(1))) void*)gp, \
          (__attribute__((address_space(3))) void*)(l0 + s * 4096), 16, 0, 0); } }

  #define LOAD_A(P, MH) { _Pragma("unroll") for (int j = 0; j < 4; ++j) \
    _Pragma("unroll") for (int kk = 0; kk < 2; ++kk) { \
      const int r_ = (MH) * 64 + j * 16 + l15; const int c_ = (kk * 4 + l4) ^ (r_ & 7); \
      aF[j][kk] = *(const bf16x8*)((P) + r_ * 64 + c_ * 8); } }

  #define LOAD_B(P, NH) { _Pragma("unroll") for (int j = 0; j < 2; ++j) \
    _Pragma("unroll") for (int kk = 0; kk < 2; ++kk) { \
      const int r_ = qB * 64 + (NH) * 32 + j * 16 + l15; const int c_ = (kk * 4 + l4) ^ (r_ & 7); \
      bF[NH][j][kk] = *(const bf16x8*)((P) + r_ * 64 + c_ * 8); } }

  #define MM(MH, NH) { __builtin_amdgcn_s_setprio(1); \
    _Pragma("unroll") for (int j = 0; j < 4; ++j) \
      _Pragma("unroll") for (int j2 = 0; j2 < 2; ++j2) \
        _Pragma("unroll") for (int kk = 0; kk < 2; ++kk) \
          acc[(MH) * 4 + j][(NH) * 2 + j2] = __builtin_amdgcn_mfma_f32_16x16x32_bf16( \
              aF[j][kk], bF[NH][j2][kk], acc[(MH) * 4 + j][(NH) * 2 + j2], 0, 0, 0); \
    __builtin_amdgcn_s_setprio(0); }

  #define BAR __builtin_amdgcn_s_barrier()
  #define WLG { asm volatile("s_waitcnt lgkmcnt(0)" ::: "memory"); __builtin_amdgcn_sched_barrier(0); }
  #define WV4 asm volatile("s_waitcnt vmcnt(4)" ::: "memory")
  #define WV0 asm volatile("s_waitcnt vmcnt(0)" ::: "memory")

  // Prologue: B(0),A(0) -> db0; B(1) -> db1. Wait first 4 half-tiles, keep B(1) in flight.
  STAGE(0, 0, 1, 0); STAGE(0, 0, 1, 1);
  STAGE(0, 0, 0, 0); STAGE(0, 0, 0, 1);
  STAGE(1, 1, 1, 0); STAGE(1, 1, 1, 1);
  WV4; BAR;

  const int NI = NT / 2 - 1;
  for (int i = 0; i < NI; ++i) {
    const int t1 = 2 * i + 1, u0 = 2 * i + 2, u1 = 2 * i + 3;
    // ph0: read A(2i)mh0 + B(2i)nh0 (db0); stage A(t1)lo -> db1
    LOAD_A(pA0, 0); LOAD_B(pB0, 0); STAGE(t1, 1, 0, 0); BAR; WLG; MM(0, 0); BAR;
    // ph1: read B nh1; stage A(t1)hi
    LOAD_B(pB0, 1); STAGE(t1, 1, 0, 1); BAR; WLG; MM(0, 1); BAR;
    // ph2: read A mh1; stage B(u0)lo -> db0 (B slot freed after ph1)
    LOAD_A(pA0, 1); STAGE(u0, 0, 1, 0); BAR; WLG; MM(1, 1); BAR;
    // ph3: stage B(u0)hi; wait B(t1)+A(t1) landed (keep B(u0) in flight)
    STAGE(u0, 0, 1, 1); BAR; WLG; MM(1, 0); WV4; BAR;
    // ph4-7: tile 2i+1 from db1; stage A(u0) -> db0, B(u1) -> db1
    LOAD_A(pA1, 0); LOAD_B(pB1, 0); STAGE(u0, 0, 0, 0); BAR; WLG; MM(0, 0); BAR;
    LOAD_B(pB1, 1); STAGE(u0, 0, 0, 1); BAR; WLG; MM(0, 1); BAR;
    LOAD_A(pA1, 1); STAGE(u1, 1, 1, 0); BAR; WLG; MM(1, 1); BAR;
    STAGE(u1, 1, 1, 1); BAR; WLG; MM(1, 0); WV4; BAR;
  }
  // Epilogue iter: tiles NT-2 (db0), NT-1 (db1); only A(NT-1) still to stage.
  {
    const int t1 = NT - 1;
    LOAD_A(pA0, 0); LOAD_B(pB0, 0); STAGE(t1, 1, 0, 0); BAR; WLG; MM(0, 0); BAR;
    LOAD_B(pB0, 1); STAGE(t1, 1, 0, 1); BAR; WLG; MM(0, 1); BAR;
    LOAD_A(pA0, 1); BAR; WLG; MM(1, 1); BAR;
    BAR; WLG; MM(1, 0); WV0; BAR;
    LOAD_A(pA1, 0); LOAD_B(pB1, 0); BAR; WLG; MM(0, 0); BAR;
    LOAD_B(pB1, 1); BAR; WLG; MM(0, 1); BAR;
    LOAD_A(pA1, 1); BAR; WLG; MM(1, 1); BAR;
    MM(1, 0);
  }
  #undef STAGE
  #undef LOAD_A
  #undef LOAD_B
  #undef MM
  #undef BAR
  #undef WLG
  #undef WV4
  #undef WV0

  u16* outp = (z < zSwitch) ? (Co + (size_t)z * sC) : (Co2 + (size_t)(z - zSwitch) * sC);
  const int gm0 = bm * 256 + wm * 128 + l4 * 4;
  const int gn0 = bn * 256 + wn * 64 + l15;
  #pragma unroll
  for (int m = 0; m < 8; ++m) {
    #pragma unroll
    for (int j = 0; j < 4; ++j) {
      const size_t rowoff = (size_t)(gm0 + m * 16 + j) * Nld;
      #pragma unroll
      for (int n = 0; n < 4; ++n) {
        float v = acc[m][n][j];
        if (SCALED) v *= scale;
        outp[rowoff + gn0 + n * 16] = f2b(v);
      }
    }
  }
}

// ---------------- row softmax in place on S (bf16), one wave per row ----------------
__global__ __launch_bounds__(256) void softmax_rows(u16* __restrict__ S) {
  int row = blockIdx.x * 4 + (threadIdx.x >> 6);
  int lane = threadIdx.x & 63;
  s16x8* p = (s16x8*)(S + (size_t)row * 4096);
  float v[64];
  float m = -1e30f;
  #pragma unroll
  for (int j = 0; j < 8; ++j) {
    s16x8 raw = p[j * 64 + lane];
    #pragma unroll
    for (int e = 0; e < 8; ++e) {
      float f = b2f((u16)raw[e]);
      v[j * 8 + e] = f;
      m = fmaxf(m, f);
    }
  }
  #pragma unroll
  for (int o = 32; o; o >>= 1) m = fmaxf(m, __shfl_xor(m, o));
  float s = 0.f;
  #pragma unroll
  for (int i = 0; i < 64; ++i) { v[i] = __expf(v[i] - m); s += v[i]; }
  #pragma unroll
  for (int o = 32; o; o >>= 1) s += __shfl_xor(s, o);
  float r = 1.f / s;
  #pragma unroll
  for (int j = 0; j < 8; ++j) {
    s16x8 o8;
    #pragma unroll
    for (int e = 0; e < 8; ++e) o8[e] = (short)f2b(v[j * 8 + e] * r);
    p[j * 64 + lane] = o8;
  }
}

// ---------------- PV split-K reduce: aoT = sum of 4 bf16 partial slices ----------------
__global__ __launch_bounds__(256) void reduce_pv(const u16* __restrict__ P, const u16* __restrict__ P2,
                                                 u16* __restrict__ ao) {
  const size_t e = ((size_t)blockIdx.x * 256 + threadIdx.x) * 8;  // < 4194304
  const int b = (int)(e >> 21);
  const size_t o = e & 2097151;
  float s[8] = {0.f, 0.f, 0.f, 0.f, 0.f, 0.f, 0.f, 0.f};
  #pragma unroll
  for (int kz = 0; kz < 4; ++kz) {
    const int zz = b * 4 + kz;
    const u16* src = (zz < 6) ? (P + (size_t)zz * 2097152) : (P2 + (size_t)(zz - 6) * 2097152);
    s16x8 v = *(const s16x8*)(src + o);
    #pragma unroll
    for (int j = 0; j < 8; ++j) s[j] += b2f((u16)v[j]);
  }
  s16x8 o8;
  #pragma unroll
  for (int j = 0; j < 8; ++j) o8[j] = (short)f2b(s[j]);
  *(s16x8*)(ao + e) = o8;
}

extern "C" void kernel_launch(void* const* d_in, const int* in_sizes, int n_in,
                              void* d_out, int out_size, void* d_ws, size_t ws_size,
                              hipStream_t stream) {
  (void)in_sizes; (void)n_in; (void)out_size; (void)ws_size;
  const float* x     = (const float*)d_in[0];
  const float* gamma = (const float*)d_in[1];
  const float* beta  = (const float*)d_in[2];
  const float* wq    = (const float*)d_in[3];
  const float* bq    = (const float*)d_in[4];
  const float* wk    = (const float*)d_in[5];
  const float* bk    = (const float*)d_in[6];
  const float* wv    = (const float*)d_in[7];
  const float* bv    = (const float*)d_in[8];
  const float* wo    = (const float*)d_in[9];
  const float* bo    = (const float*)d_in[10];

  char* ws = (char*)d_ws;
  const size_t MiB = 1024 * 1024;
  float* stats = (float*)ws;                         // 1 KiB
  u16* wbf = (u16*)(ws + 1024);                      // 2 MiB (wq|wk|wv|wo bf16)
  u16* vv  = (u16*)(ws + 4 * MiB);                   // 8 MiB
  u16* hnT = (u16*)(ws + 12 * MiB);                  // 8 MiB
  u16* qT  = (u16*)(ws + 20 * MiB);                  // 8 MiB
  u16* kT  = (u16*)(ws + 28 * MiB);                  // 8 MiB
  u16* Ppart = (u16*)(ws + 12 * MiB);                // 24 MiB (over dead hnT/qT/kT) = slices 0..5
  u16* Sm  = (u16*)(ws + 36 * MiB);                  // 64 MiB
  u16* aoT = (u16*)(ws + 36 * MiB);                  // 8 MiB (over dead Sm)

  const long long sTok = (long long)HW * C;   // 2097152
  const long long sS   = (long long)HW * HW;  // 16777216
  const float scale = 0.044194173824159216f;  // 512^-0.5

  cvt_w<<<dim3(1024), dim3(256), 0, stream>>>(wq, wk, wv, wo, wbf);
  gn_stats<<<dim3(64), dim3(1024), 0, stream>>>(x, stats);
  gn_normT<<<dim3(HW / 64, C / 64, BATCH), dim3(256), 0, stream>>>(x, stats, gamma, beta, hnT);

  // qT[b][i][o], kT[b][i][o]
  gemm_bt<EPI_BIAS_N><<<dim3(4, 32, BATCH), dim3(256), 0, stream>>>(
      hnT, wbf + 0 * 262144, qT, HW, C, C, sTok, 0, sTok, bq, nullptr, 0);
  gemm_bt<EPI_BIAS_N><<<dim3(4, 32, BATCH), dim3(256), 0, stream>>>(
      hnT, wbf + 1 * 262144, kT, HW, C, C, sTok, 0, sTok, bk, nullptr, 0);
  // vv[b][c][j]
  gemm_bt<EPI_BIAS_M><<<dim3(32, 4, BATCH), dim3(256), 0, stream>>>(
      wbf + 2 * 262144, hnT, vv, C, HW, C, 0, sTok, sTok, bv, nullptr, 0);

  // S[b][i][j] = scale * qT . kT^T   (8-phase 256^2)
  gemm256<true><<<dim3(16, 16, BATCH), dim3(512), 0, stream>>>(
      qT, kT, Sm, Sm, 1000, HW, C, 0, C, sTok, sTok, sS, scale);

  softmax_rows<<<dim3(2048), dim3(256), 0, stream>>>(Sm);

  // aoT partials: P . vv^T, split-K=4; slices 0..5 in ws, 6..7 borrow d_out
  gemm256<false><<<dim3(2, 16, BATCH * 4), dim3(512), 0, stream>>>(
      Sm, vv, Ppart, (u16*)d_out, 6, C, HW, 2, HW / 4, sS, sTok, (long long)2097152, 1.f);

  reduce_pv<<<dim3(2048), dim3(256), 0, stream>>>(Ppart, (const u16*)d_out, aoT);

  // out[b][o][i] = x + bo + wo . aoT^T
  gemm_bt<EPI_BIAS_M | EPI_RESID | EPI_F32OUT><<<dim3(32, 4, BATCH), dim3(256), 0, stream>>>(
      wbf + 3 * 262144, aoT, d_out, C, HW, C, 0, sTok, (long long)C * HW, bo, x, (long long)C * HW);
}

// Round 3
// 178.854 us; speedup vs baseline: 1.2384x; 1.0664x over previous
//
#include <hip/hip_runtime.h>
#include <hip/hip_bf16.h>

using u16 = unsigned short;
typedef __attribute__((ext_vector_type(4))) float f32x4;
typedef __attribute__((ext_vector_type(8))) __bf16 bf16x8;
typedef __attribute__((ext_vector_type(8))) short s16x8;
typedef __attribute__((ext_vector_type(4))) short s16x4;

#define DEVI __device__ __forceinline__

constexpr int BATCH = 2, C = 512, HW = 4096, NG = 32, CPG = 16;

DEVI float b2f(u16 u) { union { unsigned u; float f; } a; a.u = ((unsigned)u) << 16; return a.f; }
DEVI u16 f2b(float f) {
  union { float f; unsigned u; } a; a.f = f;
  unsigned r = a.u + 0x7fffu + ((a.u >> 16) & 1u);
  return (u16)(r >> 16);
}

// XCD-chunked bijective block remap (all grids here are multiples of 8).
DEVI void xcd_remap(int& bx, int& by, int& bz) {
  const int nx = gridDim.x, ny = gridDim.y;
  const int nwg = nx * ny * gridDim.z;
  const int flat = blockIdx.x + nx * (blockIdx.y + ny * blockIdx.z);
  const int cpx = nwg >> 3;
  const int w = (flat & 7) * cpx + (flat >> 3);
  bx = w % nx;
  const int t = w / nx;
  by = t % ny;
  bz = t / ny;
}

// ---------------- fp32 weights -> bf16 ----------------
__global__ __launch_bounds__(256) void cvt_w(const float* __restrict__ a, const float* __restrict__ b,
                                             const float* __restrict__ c, const float* __restrict__ d,
                                             u16* __restrict__ out) {
  int i = blockIdx.x * 256 + threadIdx.x;
  int w = i >> 16;
  int off = (i & 65535) * 4;
  const float* s = (w == 0) ? a : (w == 1) ? b : (w == 2) ? c : d;
  f32x4 v = *(const f32x4*)(s + off);
  s16x4 o;
  o[0] = (short)f2b(v[0]); o[1] = (short)f2b(v[1]); o[2] = (short)f2b(v[2]); o[3] = (short)f2b(v[3]);
  *(s16x4*)(out + (size_t)w * 262144 + off) = o;
}

// ---------------- GroupNorm stats ----------------
__global__ __launch_bounds__(1024) void gn_stats(const float* __restrict__ x, float* __restrict__ stats) {
  int bg = blockIdx.x;
  const f32x4* xg = (const f32x4*)(x + (size_t)bg * (CPG * HW));
  float s = 0.f, ss = 0.f;
  for (int i = threadIdx.x; i < CPG * HW / 4; i += 1024) {
    f32x4 v = xg[i];
    s += v[0] + v[1] + v[2] + v[3];
    ss += v[0] * v[0] + v[1] * v[1] + v[2] * v[2] + v[3] * v[3];
  }
  #pragma unroll
  for (int o = 32; o; o >>= 1) { s += __shfl_xor(s, o); ss += __shfl_xor(ss, o); }
  __shared__ float red[32];
  int wv = threadIdx.x >> 6, ln = threadIdx.x & 63;
  if (ln == 0) { red[wv] = s; red[16 + wv] = ss; }
  __syncthreads();
  if (threadIdx.x == 0) {
    float S = 0.f, SS = 0.f;
    for (int i = 0; i < 16; ++i) { S += red[i]; SS += red[16 + i]; }
    float inv = 1.f / (float)(CPG * HW);
    float mean = S * inv;
    float var = SS * inv - mean * mean;
    stats[bg * 2] = mean;
    stats[bg * 2 + 1] = rsqrtf(var + 1e-6f);
  }
}

// ---------------- normalize + transpose ----------------
__global__ __launch_bounds__(256) void gn_normT(const float* __restrict__ x, const float* __restrict__ stats,
                                                const float* __restrict__ gamma, const float* __restrict__ beta,
                                                u16* __restrict__ hnT) {
  __shared__ u16 tile[64][66];
  int b = blockIdx.z, c0 = blockIdx.y * 64, h0 = blockIdx.x * 64;
  int t = threadIdx.x;
  const float* xb = x + ((size_t)b * C + c0) * HW + h0;
  int r = t / 16, cc = (t % 16) * 4;
  #pragma unroll
  for (int it = 0; it < 4; ++it) {
    int rr = it * 16 + r;
    int ch = c0 + rr;
    int g = b * NG + (ch >> 4);
    float mean = stats[g * 2], rstd = stats[g * 2 + 1];
    float ga = gamma[ch] * rstd;
    float be = beta[ch] - mean * ga;
    f32x4 v = *(const f32x4*)(xb + (size_t)rr * HW + cc);
    #pragma unroll
    for (int j = 0; j < 4; ++j) tile[rr][cc + j] = f2b(v[j] * ga + be);
  }
  __syncthreads();
  u16* op = hnT + (size_t)b * HW * C + (size_t)h0 * C + c0;
  int hr2 = t / 8, cg = (t % 8) * 8;
  #pragma unroll
  for (int it = 0; it < 2; ++it) {
    int hr = it * 32 + hr2;
    s16x8 o8;
    #pragma unroll
    for (int j = 0; j < 8; ++j) o8[j] = (short)tile[cg + j][hr];
    *(s16x8*)(op + (size_t)hr * C + cg) = o8;
  }
}

// ---------------- small GEMM (128x128 m97-style), for projections ----------------
#define EPI_BIAS_M 1
#define EPI_BIAS_N 2
#define EPI_RESID  4
#define EPI_F32OUT 8
#define EPI_QK     32

template <int EPI>
__global__ __launch_bounds__(256) void gemm_bt(const u16* __restrict__ A, const u16* __restrict__ Bt,
                                               void* __restrict__ Co, int M, int N, int K,
                                               long long sA, long long sB, long long sC,
                                               const float* __restrict__ bias,
                                               const float* __restrict__ biasB,
                                               const float* __restrict__ resid, long long sR) {
  (void)M;
  __shared__ u16 ldsA[128 * 64];
  __shared__ u16 ldsB[128 * 64];
  const int tid = threadIdx.x;
  int bn, bm, bz;
  xcd_remap(bn, bm, bz);
  A += (size_t)bz * sA;
  Bt += (size_t)bz * sB;
  const int wave = tid >> 6, lane = tid & 63;
  const int wr = wave >> 1, wc = wave & 1;
  f32x4 acc[4][4] = {};

  const int srow = tid >> 3;
  const int sch = (tid & 7) ^ (srow & 7);
  const u16* gA = A + (size_t)(bm * 128 + srow) * K + sch * 8;
  const u16* gB = Bt + (size_t)(bn * 128 + srow) * K + sch * 8;
  u16* lA = ldsA + wave * 512;
  u16* lB = ldsB + wave * 512;

  for (int k0 = 0; k0 < K; k0 += 64) {
    #pragma unroll
    for (int cc = 0; cc < 4; ++cc) {
      __builtin_amdgcn_global_load_lds(
          (const __attribute__((address_space(1))) void*)(gA + (size_t)cc * 32 * K + k0),
          (__attribute__((address_space(3))) void*)(lA + cc * 2048), 16, 0, 0);
      __builtin_amdgcn_global_load_lds(
          (const __attribute__((address_space(1))) void*)(gB + (size_t)cc * 32 * K + k0),
          (__attribute__((address_space(3))) void*)(lB + cc * 2048), 16, 0, 0);
    }
    __syncthreads();
    #pragma unroll
    for (int kk = 0; kk < 2; ++kk) {
      bf16x8 af[4], bfv[4];
      #pragma unroll
      for (int m = 0; m < 4; ++m) {
        int r = wr * 64 + m * 16 + (lane & 15);
        int chunk = (kk * 4 + (lane >> 4)) ^ (r & 7);
        af[m] = *(const bf16x8*)(ldsA + r * 64 + chunk * 8);
      }
      #pragma unroll
      for (int n = 0; n < 4; ++n) {
        int r = wc * 64 + n * 16 + (lane & 15);
        int chunk = (kk * 4 + (lane >> 4)) ^ (r & 7);
        bfv[n] = *(const bf16x8*)(ldsB + r * 64 + chunk * 8);
      }
      #pragma unroll
      for (int m = 0; m < 4; ++m)
        #pragma unroll
        for (int n = 0; n < 4; ++n)
          acc[m][n] = __builtin_amdgcn_mfma_f32_16x16x32_bf16(af[m], bfv[n], acc[m][n], 0, 0, 0);
    }
    __syncthreads();
  }

  const int col0 = bn * 128 + wc * 64;
  const int row0 = bm * 128 + wr * 64 + ((lane >> 4) << 2);
  #pragma unroll
  for (int m = 0; m < 4; ++m) {
    #pragma unroll
    for (int j = 0; j < 4; ++j) {
      int gm = row0 + m * 16 + j;
      float bm_v = (EPI & EPI_BIAS_M) ? bias[gm] : 0.f;
      #pragma unroll
      for (int n = 0; n < 4; ++n) {
        int gn = col0 + n * 16 + (lane & 15);
        float v = acc[m][n][j] + bm_v;
        if (EPI & EPI_BIAS_N) {
          if (EPI & EPI_QK) v += (gn < 512) ? bias[gn] : biasB[gn - 512];
          else v += bias[gn];
        }
        if (EPI & EPI_RESID) v += resid[(size_t)bz * sR + (size_t)gm * N + gn];
        if (EPI & EPI_F32OUT)
          ((float*)Co)[(size_t)bz * sC + (size_t)gm * N + gn] = v;
        else
          ((u16*)Co)[(size_t)bz * sC + (size_t)gm * N + gn] = f2b(v);
      }
    }
  }
}

// ---------------- big GEMM: 256x256 tile, 8-phase schedule, counted vmcnt ----------------
template <bool SCALED>
__global__ __launch_bounds__(512, 2) void gemm256(
    const u16* __restrict__ Ag, const u16* __restrict__ Bg,
    u16* __restrict__ Co, u16* __restrict__ Co2, int zSwitch,
    int Nld, int ldK, int nsplitLog, int kLen,
    long long sA, long long sB, long long sC, float scale) {
  __shared__ u16 lds[65536];  // staging [db][A/B][half] x (128x64); reused as C-tile in epilogue
  const int tid = threadIdx.x;
  const int lane = tid & 63, w = tid >> 6;
  const int wm = w >> 2, wn = w & 3;
  const int l15 = lane & 15, l4 = lane >> 4;
  int bn, bm, z;
  xcd_remap(bn, bm, z);
  const int bz = z >> nsplitLog, kz = z & ((1 << nsplitLog) - 1);
  const int kStart = kz * kLen;
  const int NT = kLen >> 6;

  const int rStage = w * 8 + (lane >> 3);
  const int gch = (lane & 7) ^ (lane >> 3);
  const u16* gA = Ag + (size_t)bz * sA + (size_t)(bm * 256) * ldK + kStart + gch * 8;
  const u16* gB = Bg + (size_t)bz * sB + (size_t)(bn * 256) * ldK + kStart + gch * 8;

  f32x4 acc[8][4] = {};
  bf16x8 aF[4][2], bF[2][2][2];

  const int hB = wn >> 1, qB = wn & 1;
  const u16* pA0 = lds + (0 * 4 + wm) * 8192;
  const u16* pA1 = lds + (1 * 4 + wm) * 8192;
  const u16* pB0 = lds + (0 * 4 + 2 + hB) * 8192;
  const u16* pB1 = lds + (1 * 4 + 2 + hB) * 8192;

  #define STAGE(TT, DB, AB, HF) { \
    const u16* gbase = (AB) ? gB : gA; \
    u16* l0 = lds + ((DB) * 4 + (AB) * 2 + (HF)) * 8192 + w * 512; \
    _Pragma("unroll") for (int s = 0; s < 2; ++s) { \
      const u16* gp = gbase + (size_t)((HF) * 128 + s * 64 + rStage) * ldK + (TT) * 64; \
      __builtin_amdgcn_global_load_lds((const __attribute__((address_space(1))) void*)gp, \
          (__attribute__((address_space(3))) void*)(l0 + s * 4096), 16, 0, 0); } }

  #define LOAD_A(P, MH) { _Pragma("unroll") for (int j = 0; j < 4; ++j) \
    _Pragma("unroll") for (int kk = 0; kk < 2; ++kk) { \
      const int r_ = (MH) * 64 + j * 16 + l15; const int c_ = (kk * 4 + l4) ^ (r_ & 7); \
      aF[j][kk] = *(const bf16x8*)((P) + r_ * 64 + c_ * 8); } }

  #define LOAD_B(P, NH) { _Pragma("unroll") for (int j = 0; j < 2; ++j) \
    _Pragma("unroll") for (int kk = 0; kk < 2; ++kk) { \
      const int r_ = qB * 64 + (NH) * 32 + j * 16 + l15; const int c_ = (kk * 4 + l4) ^ (r_ & 7); \
      bF[NH][j][kk] = *(const bf16x8*)((P) + r_ * 64 + c_ * 8); } }

  #define MM(MH, NH) { __builtin_amdgcn_s_setprio(1); \
    _Pragma("unroll") for (int j = 0; j < 4; ++j) \
      _Pragma("unroll") for (int j2 = 0; j2 < 2; ++j2) \
        _Pragma("unroll") for (int kk = 0; kk < 2; ++kk) \
          acc[(MH) * 4 + j][(NH) * 2 + j2] = __builtin_amdgcn_mfma_f32_16x16x32_bf16( \
              aF[j][kk], bF[NH][j2][kk], acc[(MH) * 4 + j][(NH) * 2 + j2], 0, 0, 0); \
    __builtin_amdgcn_s_setprio(0); }

  #define BAR __builtin_amdgcn_s_barrier()
  #define WLG { asm volatile("s_waitcnt lgkmcnt(0)" ::: "memory"); __builtin_amdgcn_sched_barrier(0); }
  #define WV4 asm volatile("s_waitcnt vmcnt(4)" ::: "memory")
  #define WV0 asm volatile("s_waitcnt vmcnt(0)" ::: "memory")

  STAGE(0, 0, 1, 0); STAGE(0, 0, 1, 1);
  STAGE(0, 0, 0, 0); STAGE(0, 0, 0, 1);
  STAGE(1, 1, 1, 0); STAGE(1, 1, 1, 1);
  WV4; BAR;

  const int NI = NT / 2 - 1;
  for (int i = 0; i < NI; ++i) {
    const int t1 = 2 * i + 1, u0 = 2 * i + 2, u1 = 2 * i + 3;
    LOAD_A(pA0, 0); LOAD_B(pB0, 0); STAGE(t1, 1, 0, 0); BAR; WLG; MM(0, 0); BAR;
    LOAD_B(pB0, 1); STAGE(t1, 1, 0, 1); BAR; WLG; MM(0, 1); BAR;
    LOAD_A(pA0, 1); STAGE(u0, 0, 1, 0); BAR; WLG; MM(1, 1); BAR;
    STAGE(u0, 0, 1, 1); BAR; WLG; MM(1, 0); WV4; BAR;
    LOAD_A(pA1, 0); LOAD_B(pB1, 0); STAGE(u0, 0, 0, 0); BAR; WLG; MM(0, 0); BAR;
    LOAD_B(pB1, 1); STAGE(u0, 0, 0, 1); BAR; WLG; MM(0, 1); BAR;
    LOAD_A(pA1, 1); STAGE(u1, 1, 1, 0); BAR; WLG; MM(1, 1); BAR;
    STAGE(u1, 1, 1, 1); BAR; WLG; MM(1, 0); WV4; BAR;
  }
  {
    const int t1 = NT - 1;
    LOAD_A(pA0, 0); LOAD_B(pB0, 0); STAGE(t1, 1, 0, 0); BAR; WLG; MM(0, 0); BAR;
    LOAD_B(pB0, 1); STAGE(t1, 1, 0, 1); BAR; WLG; MM(0, 1); BAR;
    LOAD_A(pA0, 1); BAR; WLG; MM(1, 1); BAR;
    BAR; WLG; MM(1, 0); WV0; BAR;
    LOAD_A(pA1, 0); LOAD_B(pB1, 0); BAR; WLG; MM(0, 0); BAR;
    LOAD_B(pB1, 1); BAR; WLG; MM(0, 1); BAR;
    LOAD_A(pA1, 1); BAR; WLG; MM(1, 1); BAR;
    MM(1, 0);
  }
  #undef STAGE
  #undef LOAD_A
  #undef LOAD_B
  #undef MM
  #undef BAR
  #undef WLG
  #undef WV4
  #undef WV0

  // ---- epilogue: repack C-tile through LDS (XOR-swizzled), coalesced 16B stores ----
  // LDS staging reads are all drained (last phase: LOAD -> BAR after WLG), safe to overwrite.
  {
    const int rloc = wm * 128 + l4 * 4;
    const int cloc = wn * 64 + l15;
    #pragma unroll
    for (int m = 0; m < 8; ++m) {
      #pragma unroll
      for (int j = 0; j < 4; ++j) {
        const int r_ = rloc + m * 16 + j;
        const int xr = ((r_ >> 2) & 3) << 5;
        #pragma unroll
        for (int n = 0; n < 4; ++n) {
          float v = acc[m][n][j];
          if (SCALED) v *= scale;
          *(u16*)((char*)lds + ((r_ * 512 + (cloc + n * 16) * 2) ^ xr)) = f2b(v);
        }
      }
    }
    __syncthreads();
    u16* outp = (z < zSwitch) ? (Co + (size_t)z * sC) : (Co2 + (size_t)(z - zSwitch) * sC);
    #pragma unroll
    for (int it = 0; it < 16; ++it) {
      const int idx = it * 512 + tid;
      const int r_ = idx >> 5, ch = idx & 31;
      const int xr = ((r_ >> 2) & 3) << 5;
      s16x8 d8 = *(const s16x8*)((const char*)lds + ((r_ * 512 + ch * 16) ^ xr));
      *(s16x8*)(outp + (size_t)(bm * 256 + r_) * Nld + bn * 256 + ch * 8) = d8;
    }
  }
}

// ---------------- row softmax in place on S (bf16), one wave per row ----------------
__global__ __launch_bounds__(256) void softmax_rows(u16* __restrict__ S) {
  int row = blockIdx.x * 4 + (threadIdx.x >> 6);
  int lane = threadIdx.x & 63;
  s16x8* p = (s16x8*)(S + (size_t)row * 4096);
  float v[64];
  float m = -1e30f;
  #pragma unroll
  for (int j = 0; j < 8; ++j) {
    s16x8 raw = p[j * 64 + lane];
    #pragma unroll
    for (int e = 0; e < 8; ++e) {
      float f = b2f((u16)raw[e]);
      v[j * 8 + e] = f;
      m = fmaxf(m, f);
    }
  }
  #pragma unroll
  for (int o = 32; o; o >>= 1) m = fmaxf(m, __shfl_xor(m, o));
  float s = 0.f;
  #pragma unroll
  for (int i = 0; i < 64; ++i) { v[i] = __expf(v[i] - m); s += v[i]; }
  #pragma unroll
  for (int o = 32; o; o >>= 1) s += __shfl_xor(s, o);
  float r = 1.f / s;
  #pragma unroll
  for (int j = 0; j < 8; ++j) {
    s16x8 o8;
    #pragma unroll
    for (int e = 0; e < 8; ++e) o8[e] = (short)f2b(v[j * 8 + e] * r);
    p[j * 64 + lane] = o8;
  }
}

// ---------------- PV split-K reduce ----------------
__global__ __launch_bounds__(256) void reduce_pv(const u16* __restrict__ P, const u16* __restrict__ P2,
                                                 u16* __restrict__ ao) {
  const size_t e = ((size_t)blockIdx.x * 256 + threadIdx.x) * 8;
  const int b = (int)(e >> 21);
  const size_t o = e & 2097151;
  float s[8] = {0.f, 0.f, 0.f, 0.f, 0.f, 0.f, 0.f, 0.f};
  #pragma unroll
  for (int kz = 0; kz < 4; ++kz) {
    const int zz = b * 4 + kz;
    const u16* src = (zz < 6) ? (P + (size_t)zz * 2097152) : (P2 + (size_t)(zz - 6) * 2097152);
    s16x8 v = *(const s16x8*)(src + o);
    #pragma unroll
    for (int j = 0; j < 8; ++j) s[j] += b2f((u16)v[j]);
  }
  s16x8 o8;
  #pragma unroll
  for (int j = 0; j < 8; ++j) o8[j] = (short)f2b(s[j]);
  *(s16x8*)(ao + e) = o8;
}

extern "C" void kernel_launch(void* const* d_in, const int* in_sizes, int n_in,
                              void* d_out, int out_size, void* d_ws, size_t ws_size,
                              hipStream_t stream) {
  (void)in_sizes; (void)n_in; (void)out_size; (void)ws_size;
  const float* x     = (const float*)d_in[0];
  const float* gamma = (const float*)d_in[1];
  const float* beta  = (const float*)d_in[2];
  const float* wq    = (const float*)d_in[3];
  const float* bq    = (const float*)d_in[4];
  const float* wk    = (const float*)d_in[5];
  const float* bk    = (const float*)d_in[6];
  const float* wv    = (const float*)d_in[7];
  const float* bv    = (const float*)d_in[8];
  const float* wo    = (const float*)d_in[9];
  const float* bo    = (const float*)d_in[10];

  char* ws = (char*)d_ws;
  const size_t MiB = 1024 * 1024;
  float* stats = (float*)ws;                    // 1 KiB
  u16* wbf = (u16*)(ws + 1024);                 // 2 MiB: wq|wk|wv|wo bf16 (wq,wk contiguous -> 1024 rows)
  u16* vv  = (u16*)(ws + 4 * MiB);              // 8 MiB  [b][c][j]
  u16* qkT = (u16*)(ws + 12 * MiB);             // 16 MiB [b][i][1024] (q:0..511, k:512..1023)
  u16* hnT = (u16*)(ws + 28 * MiB);             // 8 MiB  [b][i][c]
  u16* Ppart = (u16*)(ws + 12 * MiB);           // 24 MiB over dead qkT/hnT: PV partial slices 0..5
  u16* Sm  = (u16*)(ws + 36 * MiB);             // 64 MiB
  u16* aoT = (u16*)(ws + 36 * MiB);             // 8 MiB over dead Sm

  const long long sTok  = (long long)HW * C;     // 2097152
  const long long sTok2 = (long long)HW * 1024;  // 4194304
  const long long sS    = (long long)HW * HW;    // 16777216
  const float scale = 0.044194173824159216f;     // 512^-0.5

  cvt_w<<<dim3(1024), dim3(256), 0, stream>>>(wq, wk, wv, wo, wbf);
  gn_stats<<<dim3(64), dim3(1024), 0, stream>>>(x, stats);
  gn_normT<<<dim3(HW / 64, C / 64, BATCH), dim3(256), 0, stream>>>(x, stats, gamma, beta, hnT);

  // qkT[b][i][0..1023] = hnT . [wq|wk]^T + [bq|bk]   (fused q+k projection)
  gemm_bt<EPI_BIAS_N | EPI_QK><<<dim3(8, 32, BATCH), dim3(256), 0, stream>>>(
      hnT, wbf, qkT, HW, 1024, C, sTok, 0, sTok2, bq, bk, nullptr, 0);
  // vv[b][c][j] = wv . hnT^T + bv
  gemm_bt<EPI_BIAS_M><<<dim3(32, 4, BATCH), dim3(256), 0, stream>>>(
      wbf + 2 * 262144, hnT, vv, C, HW, C, 0, sTok, sTok, bv, nullptr, nullptr, 0);

  // S[b][i][j] = scale * q . k^T   (8-phase 256^2; A,B rows stride 1024)
  gemm256<true><<<dim3(16, 16, BATCH), dim3(512), 0, stream>>>(
      qkT, qkT + 512, Sm, Sm, 1000, HW, 1024, 0, C, sTok2, sTok2, sS, scale);

  softmax_rows<<<dim3(2048), dim3(256), 0, stream>>>(Sm);

  // aoT partials: P . vv^T, split-K=4; slices 0..5 in ws, 6..7 borrow d_out
  gemm256<false><<<dim3(2, 16, BATCH * 4), dim3(512), 0, stream>>>(
      Sm, vv, Ppart, (u16*)d_out, 6, C, HW, 2, HW / 4, sS, sTok, (long long)2097152, 1.f);

  reduce_pv<<<dim3(2048), dim3(256), 0, stream>>>(Ppart, (const u16*)d_out, aoT);

  // out[b][o][i] = x + bo + wo . aoT^T
  gemm_bt<EPI_BIAS_M | EPI_RESID | EPI_F32OUT><<<dim3(32, 4, BATCH), dim3(256), 0, stream>>>(
      wbf + 3 * 262144, aoT, d_out, C, HW, C, 0, sTok, (long long)C * HW, bo, nullptr, x, (long long)C * HW);
}